// Round 9
// baseline (311.576 us; speedup 1.0000x reference)
//
#include <hip/hip_runtime.h>
#include <hip/hip_fp16.h>

#define D_FEAT 64
#define LOG_BKT 9
#define BKT_W 512            // nodes per bucket
#define NBIN 256             // bins (N <= 131072)
#define CHUNK 2048           // edges per WG in histdump/part (489 WGs at E=1M)

// ---------------- fast path ----------------

// per-WG 512-bin histogram (row bins 0..255, col bins 256..511) -> global slab.
// Plain stores: no zeroing kernel, no global atomics.
__global__ void k_histdump(const int* __restrict__ row, const int* __restrict__ col,
                           unsigned* __restrict__ wgHist, int E) {
    __shared__ unsigned h[512];
    int t = threadIdx.x;
    h[t] = 0u; h[t + 256] = 0u;
    __syncthreads();
    long long c0 = (long long)blockIdx.x * CHUNK;
    for (int k = 0; k < CHUNK / 256; ++k) {
        long long e = c0 + (long long)k * 256 + t;
        if (e < E) {
            atomicAdd(&h[row[e] >> LOG_BKT], 1u);
            atomicAdd(&h[256 + (col[e] >> LOG_BKT)], 1u);
        }
    }
    __syncthreads();
    unsigned* dst = wgHist + (size_t)blockIdx.x * 512;
    dst[t] = h[t]; dst[t + 256] = h[t + 256];
}

// single block, 512 threads: thread b owns bin b. Serial prefix over WGs with
// coalesced row access (512 consecutive words per iteration) + 8-deep prefetch;
// then segmented 256-scan of bin totals -> baseR/baseC; sentinels.
// Replaces the old column-major scan2a (500K scattered line-ops) + scan2b.
__global__ void __launch_bounds__(512) k_binscan(
        unsigned* __restrict__ wgHist, unsigned* __restrict__ baseR,
        unsigned* __restrict__ baseC, unsigned* __restrict__ nodeBeg,
        int nWG, int E, int N) {
    __shared__ unsigned lds[512];
    int b = threadIdx.x;          // bin 0..511
    unsigned run = 0;
    unsigned buf[8];
    int pf = nWG < 8 ? nWG : 8;
    for (int i = 0; i < pf; ++i) buf[i] = wgHist[(size_t)i * 512 + b];
    for (int wg = 0; wg < nWG; ++wg) {
        unsigned v = buf[wg & 7];
        if (wg + 8 < nWG) buf[wg & 7] = wgHist[(size_t)(wg + 8) * 512 + b];
        wgHist[(size_t)wg * 512 + b] = run;   // exclusive prefix for this (wg,bin)
        run += v;
    }
    // run == binTot[b]; segmented inclusive scan (halves: row bins, col bins)
    lds[b] = run;
    __syncthreads();
    int h = b & 255;
    for (int d = 1; d < 256; d <<= 1) {
        unsigned a = (h >= d) ? lds[b - d] : 0u;
        __syncthreads();
        lds[b] += a;
        __syncthreads();
    }
    unsigned excl = lds[b] - run;
    if (b < 256) baseR[b] = excl;
    else         baseC[h] = excl;
    if (b == 0) {
        baseR[256] = (unsigned)E;
        baseC[256] = (unsigned)E;
        nodeBeg[N] = (unsigned)E;   // sentinel
    }
}

// single placement pass: cursors preloaded from slab, only LDS atomics.
__global__ void k_part2(const int* __restrict__ row, const int* __restrict__ col,
                        const unsigned* __restrict__ wgHist,
                        const unsigned* __restrict__ baseR, const unsigned* __restrict__ baseC,
                        unsigned* __restrict__ entries, unsigned short* __restrict__ colslab,
                        int E) {
    __shared__ unsigned cR[256];
    __shared__ unsigned cC[256];
    int t = threadIdx.x;
    const unsigned* my = wgHist + (size_t)blockIdx.x * 512;
    cR[t] = my[t] + baseR[t];
    cC[t] = my[t + 256] + baseC[t];
    __syncthreads();
    long long c0 = (long long)blockIdx.x * CHUNK;
    for (int k = 0; k < CHUNK / 256; ++k) {
        long long e = c0 + (long long)k * 256 + t;
        if (e < E) {
            int r = row[e], cc = col[e];
            unsigned pr = atomicAdd(&cR[r >> LOG_BKT], 1u);
            entries[pr] = ((unsigned)(r & (BKT_W - 1)) << 17) | (unsigned)cc;
            unsigned pc = atomicAdd(&cC[cc >> LOG_BKT], 1u);
            colslab[pc] = (unsigned short)(cc & (BKT_W - 1));
        }
    }
}

// fused independent mid-work: blocks [0,nBkt) do colcount (dis), [nBkt,2nBkt) localcsr.
__global__ void __launch_bounds__(256) k_mid(
        const unsigned* __restrict__ entries, unsigned* __restrict__ sorted,
        const unsigned* __restrict__ baseR, unsigned* __restrict__ nodeBeg,
        const unsigned short* __restrict__ colslab, const unsigned* __restrict__ baseC,
        float* __restrict__ dis, int N, int nBkt) {
    __shared__ unsigned shA[512];   // hist
    __shared__ unsigned shB[512];   // cur
    __shared__ unsigned shC[256];   // scan temp
    int b = blockIdx.x, t = threadIdx.x;
    if (b < nBkt) {
        // ---- colcount: dis[node] = rsqrt(cnt+1) ----
        shA[t] = 0u; shA[t + 256] = 0u;
        __syncthreads();
        unsigned s = baseC[b], e_ = baseC[b + 1];
        for (unsigned i = s + t; i < e_; i += 256) atomicAdd(&shA[colslab[i]], 1u);
        __syncthreads();
        int node0 = b << LOG_BKT;
        int n0 = node0 + t, n1 = node0 + t + 256;
        if (n0 < N) dis[n0] = rsqrtf((float)(shA[t] + 1u));
        if (n1 < N) dis[n1] = rsqrtf((float)(shA[t + 256] + 1u));
    } else {
        // ---- localcsr: per-node CSR within bucket ----
        b -= nBkt;
        shA[t] = 0u; shA[t + 256] = 0u;
        __syncthreads();
        unsigned s = baseR[b], e_ = baseR[b + 1];
        int cnt = (int)(e_ - s);
        for (int i = t; i < cnt; i += 256) atomicAdd(&shA[entries[s + i] >> 17], 1u);
        __syncthreads();
        unsigned a = shA[2 * t], bb = shA[2 * t + 1], s2 = a + bb;
        shC[t] = s2;
        __syncthreads();
        for (int d = 1; d < 256; d <<= 1) {
            unsigned ad = (t >= d) ? shC[t - d] : 0u;
            __syncthreads();
            shC[t] += ad;
            __syncthreads();
        }
        unsigned excl = shC[t] - s2;
        shB[2 * t] = excl; shB[2 * t + 1] = excl + a;
        int node0 = b << LOG_BKT;
        int n0 = node0 + 2 * t, n1 = n0 + 1;
        if (n0 < N) nodeBeg[n0] = s + excl;
        if (n1 < N) nodeBeg[n1] = s + excl + a;
        __syncthreads();
        for (int i = t; i < cnt; i += 256) {
            unsigned v = entries[s + i];
            unsigned pos = atomicAdd(&shB[v >> 17], 1u);
            sorted[s + pos] = v & 0x1FFFFu;
        }
    }
}

// xs = dis * x, fp16
__global__ void k_scale(const float* __restrict__ x, const float* __restrict__ dis,
                        __half* __restrict__ xs, int N) {
    int i = blockIdx.x * blockDim.x + threadIdx.x;
    if (i >= N * (D_FEAT / 4)) return;
    int node = i >> 4;
    float d = dis[node];
    float4 v = ((const float4*)x)[i];
    __half2 p0 = __floats2half2_rn(d * v.x, d * v.y);
    __half2 p1 = __floats2half2_rn(d * v.z, d * v.w);
    ((__half2*)xs)[i * 2]     = p0;
    ((__half2*)xs)[i * 2 + 1] = p1;
}

// per-node wave gather (proven): 2 groups x 32 lanes, lane owns feats (2m,2m+1);
// group 0 even-position cols, group 1 odd; __half2 4B loads; f32 self term;
// combine via shfl(lane^32).
__global__ void __launch_bounds__(256) k_gather(
        const float* __restrict__ x, const __half* __restrict__ xs,
        const float* __restrict__ dis, const unsigned* __restrict__ nodeBeg,
        const unsigned* __restrict__ sorted, float* __restrict__ out, int n) {
    int r = (blockIdx.x * blockDim.x + threadIdx.x) >> 6;
    int lane = threadIdx.x & 63;
    if (r >= n) return;
    int g = lane >> 5, m = lane & 31;
    float dr = dis[r];
    float2 acc;
    if (g == 0) {
        float2 xv = ((const float2*)x)[(size_t)r * 32 + m];
        acc.x = dr * xv.x; acc.y = dr * xv.y;          // self term (final *dr below)
    } else {
        acc.x = 0.f; acc.y = 0.f;
    }
    unsigned s = nodeBeg[r], e_ = nodeBeg[r + 1];
    int cnt = (int)(e_ - s);
    const __half2* xs2 = (const __half2*)xs;
    for (int base = 0; base < cnt; base += 64) {
        int mm = min(64, cnt - base);
        unsigned my_e = (lane < mm) ? sorted[s + base + lane] : 0u;
        int k = 0;
        for (; k + 8 <= mm; k += 8) {
            unsigned c0 = __shfl(my_e, k + g),     c1 = __shfl(my_e, k + 2 + g);
            unsigned c2 = __shfl(my_e, k + 4 + g), c3 = __shfl(my_e, k + 6 + g);
            float2 f0 = __half22float2(xs2[(size_t)c0 * 32 + m]);
            float2 f1 = __half22float2(xs2[(size_t)c1 * 32 + m]);
            float2 f2 = __half22float2(xs2[(size_t)c2 * 32 + m]);
            float2 f3 = __half22float2(xs2[(size_t)c3 * 32 + m]);
            acc.x += (f0.x + f1.x) + (f2.x + f3.x);
            acc.y += (f0.y + f1.y) + (f2.y + f3.y);
        }
        for (; k < mm; k += 2) {
            if (k + g < mm) {
                unsigned c = __shfl(my_e, k + g);
                float2 f = __half22float2(xs2[(size_t)c * 32 + m]);
                acc.x += f.x; acc.y += f.y;
            }
        }
    }
    acc.x += __shfl(acc.x, lane ^ 32);
    acc.y += __shfl(acc.y, lane ^ 32);
    if (g == 0) {
        float2 o; o.x = dr * acc.x; o.y = dr * acc.y;
        ((float2*)out)[(size_t)r * 32 + m] = o;
    }
}

// ---------------- fallback path (round-1 atomic scatter) ----------------

__global__ void k_init_deg(float* __restrict__ deg, int n) {
    int i = blockIdx.x * blockDim.x + threadIdx.x;
    if (i < n) deg[i] = 1.0f;
}
__global__ void k_count_deg(const int* __restrict__ col, float* __restrict__ deg, int E) {
    int e = blockIdx.x * blockDim.x + threadIdx.x;
    if (e < E) atomicAdd(&deg[col[e]], 1.0f);
}
__global__ void k_deg_to_dis(float* __restrict__ deg, int n) {
    int i = blockIdx.x * blockDim.x + threadIdx.x;
    if (i < n) deg[i] = rsqrtf(deg[i]);
}
__global__ void k_self_init(const float* __restrict__ x, const float* __restrict__ dis,
                            float* __restrict__ out, int total) {
    int idx = blockIdx.x * blockDim.x + threadIdx.x;
    if (idx < total) {
        int node = idx >> 6;
        float s = dis[node];
        out[idx] = s * s * x[idx];
    }
}
__global__ void k_scatter(const int* __restrict__ row, const int* __restrict__ col,
                          const float* __restrict__ x, const float* __restrict__ dis,
                          float* __restrict__ out, int E) {
    int gtid = blockIdx.x * blockDim.x + threadIdx.x;
    int edge = gtid >> 6;
    int lane = threadIdx.x & 63;
    if (edge < E) {
        int r = row[edge];
        int c = col[edge];
        float nrm = dis[r] * dis[c];
        atomicAdd(&out[r * D_FEAT + lane], nrm * x[c * D_FEAT + lane]);
    }
}

extern "C" void kernel_launch(void* const* d_in, const int* in_sizes, int n_in,
                              void* d_out, int out_size, void* d_ws, size_t ws_size,
                              hipStream_t stream) {
    const float* x = (const float*)d_in[0];
    const int* ei = (const int*)d_in[1];

    const int N = in_sizes[0] / D_FEAT;   // 100000
    const int E = in_sizes[1] / 2;        // 1000000
    const int* row = ei;
    const int* col = ei + E;

    float* out = (float*)d_out;
    const int B = 256;
    const int nBkt = (N + BKT_W - 1) >> LOG_BKT;
    const int nWG = (E + CHUNK - 1) / CHUNK;

    // ws words: dis[N] | baseR[257] | baseC[257] | nodeBeg[N+1] | pad
    //           | sorted[E] (wgHist[nWG*512] overlays its head until part2)
    //           | tail: max(entries[E]*4 + colslab[E]*2, xs N*128B)
    size_t preSorted = (size_t)N + 257 + 257 + (size_t)(N + 1);
    preSorted = (preSorted + 3) & ~(size_t)3;       // 16B-align sorted/entries/xs
    size_t tailBytes = (size_t)E * 6;
    size_t xsBytes = (size_t)N * D_FEAT * 2;
    if (xsBytes > tailBytes) tailBytes = xsBytes;
    size_t need = (preSorted + (size_t)E) * 4 + tailBytes;

    if (N <= 131072 && nBkt <= NBIN && nWG <= 4096 &&
        (size_t)nWG * 512 <= (size_t)E && ws_size >= need) {
        float*    dis     = (float*)d_ws;
        unsigned* baseR   = (unsigned*)(dis + N);
        unsigned* baseC   = baseR + 257;
        unsigned* nodeBeg = baseC + 257;
        unsigned* sorted  = (unsigned*)d_ws + preSorted;
        unsigned* wgHist  = sorted;                    // overlays sorted until part2
        unsigned* entries = sorted + E;                // tail
        unsigned short* colslab = (unsigned short*)(entries + E);
        __half*   xs      = (__half*)entries;          // overlays entries+colslab after mid

        k_histdump<<<nWG, B, 0, stream>>>(row, col, wgHist, E);
        k_binscan<<<1, 512, 0, stream>>>(wgHist, baseR, baseC, nodeBeg, nWG, E, N);
        k_part2<<<nWG, B, 0, stream>>>(row, col, wgHist, baseR, baseC, entries, colslab, E);
        k_mid<<<2 * nBkt, B, 0, stream>>>(entries, sorted, baseR, nodeBeg,
                                          colslab, baseC, dis, N, nBkt);
        k_scale<<<(N * (D_FEAT / 4) + B - 1) / B, B, 0, stream>>>(x, dis, xs, N);
        long long gthreads = (long long)N * 64;
        k_gather<<<(int)((gthreads + B - 1) / B), B, 0, stream>>>(
            x, xs, dis, nodeBeg, sorted, out, N);
    } else {
        // fallback: atomic scatter (needs only N floats of ws)
        float* deg = (float*)d_ws;
        k_init_deg<<<(N + B - 1) / B, B, 0, stream>>>(deg, N);
        k_count_deg<<<(E + B - 1) / B, B, 0, stream>>>(col, deg, E);
        k_deg_to_dis<<<(N + B - 1) / B, B, 0, stream>>>(deg, N);
        int total = N * D_FEAT;
        k_self_init<<<(total + B - 1) / B, B, 0, stream>>>(x, deg, out, total);
        long long st = (long long)E * 64;
        k_scatter<<<(int)((st + B - 1) / B), B, 0, stream>>>(row, col, x, deg, out, E);
    }
}

// Round 11
// 123.705 us; speedup vs baseline: 2.5187x; 2.5187x over previous
//
#include <hip/hip_runtime.h>
#include <hip/hip_fp16.h>

#define D_FEAT 64
#define LOG_BKT 9
#define BKT_W 512            // nodes per bucket
#define NBIN 256             // bins (N <= 131072)
#define CHUNK 2048           // edges per WG in histdump/part (489 WGs at E=1M)
#define MAXWG 492            // scan tile rows: 492*32*4 = 62976 B LDS

// ---------------- fast path ----------------

// per-WG 512-bin histogram (row bins 0..255, col bins 256..511) -> global slab.
// Plain stores: no zeroing kernel, no global atomics.
__global__ void k_histdump(const int* __restrict__ row, const int* __restrict__ col,
                           unsigned* __restrict__ wgHist, int E) {
    __shared__ unsigned h[512];
    int t = threadIdx.x;
    h[t] = 0u; h[t + 256] = 0u;
    __syncthreads();
    long long c0 = (long long)blockIdx.x * CHUNK;
    for (int k = 0; k < CHUNK / 256; ++k) {
        long long e = c0 + (long long)k * 256 + t;
        if (e < E) {
            atomicAdd(&h[row[e] >> LOG_BKT], 1u);
            atomicAdd(&h[256 + (col[e] >> LOG_BKT)], 1u);
        }
    }
    __syncthreads();
    unsigned* dst = wgHist + (size_t)blockIdx.x * 512;
    dst[t] = h[t]; dst[t + 256] = h[t + 256];
}

// coalesced slab scan: 16 blocks; block q owns bins [q*32, q*32+32) (one 128B
// line-width). Loads the [nWG][512] slab via full-line wave-loads into a
// transposed LDS tile, 8-chunk scan per bin, coalesced write-back.
// Replaces the column-major scan2a (~500K scattered line-ops -> ~16K coalesced).
__global__ void __launch_bounds__(256) k_scan2aT(
        unsigned* __restrict__ wgHist, unsigned* __restrict__ binTot, int nWG) {
    __shared__ unsigned tile[MAXWG * 32];   // [wg][binLocal]
    __shared__ unsigned csum[256];          // [binLocal][chunk j]
    int q = blockIdx.x;
    int t = threadIdx.x;
    int b0 = q * 32;
    int lane32 = t & 31;
    int wrow = t >> 5;                      // 0..7
    for (int w0 = 0; w0 < nWG; w0 += 8) {
        int w = w0 + wrow;
        if (w < nWG) tile[w * 32 + lane32] = wgHist[(size_t)w * 512 + b0 + lane32];
    }
    __syncthreads();
    int bl = t & 31, j = t >> 5;            // 8 chunks per bin
    int L = (nWG + 7) >> 3;
    int w_s = j * L;
    int w_e = (w_s + L < nWG) ? (w_s + L) : nWG;
    unsigned sum = 0;
    for (int w = w_s; w < w_e; ++w) sum += tile[w * 32 + bl];
    csum[bl * 8 + j] = sum;
    __syncthreads();
    if (j == 0) {                           // serial scan of 8 chunk sums per bin
        unsigned run = 0;
        for (int k = 0; k < 8; ++k) {
            unsigned v = csum[bl * 8 + k];
            csum[bl * 8 + k] = run;
            run += v;
        }
        binTot[b0 + bl] = run;
    }
    __syncthreads();
    unsigned run = csum[bl * 8 + j];
    for (int w = w_s; w < w_e; ++w) {
        unsigned v = tile[w * 32 + bl];
        tile[w * 32 + bl] = run;            // exclusive prefix for (wg,bin)
        run += v;
    }
    __syncthreads();
    for (int w0 = 0; w0 < nWG; w0 += 8) {
        int w = w0 + wrow;
        if (w < nWG) wgHist[(size_t)w * 512 + b0 + lane32] = tile[w * 32 + lane32];
    }
}

// single block: scan row-bin totals -> baseR[257], col-bin totals -> baseC[257].
__global__ void k_scan2b(const unsigned* __restrict__ binTot,
                         unsigned* __restrict__ baseR, unsigned* __restrict__ baseC,
                         unsigned* __restrict__ nodeBeg, int E, int N) {
    __shared__ unsigned lds[256];
    int t = threadIdx.x;
    unsigned v = binTot[t];
    lds[t] = v;
    __syncthreads();
    for (int d = 1; d < 256; d <<= 1) {
        unsigned a = (t >= d) ? lds[t - d] : 0u;
        __syncthreads();
        lds[t] += a;
        __syncthreads();
    }
    baseR[t] = lds[t] - v;
    if (t == 255) baseR[256] = (unsigned)E;
    __syncthreads();
    unsigned w = binTot[256 + t];
    lds[t] = w;
    __syncthreads();
    for (int d = 1; d < 256; d <<= 1) {
        unsigned a = (t >= d) ? lds[t - d] : 0u;
        __syncthreads();
        lds[t] += a;
        __syncthreads();
    }
    baseC[t] = lds[t] - w;
    if (t == 255) baseC[256] = (unsigned)E;
    if (t == 0) nodeBeg[N] = (unsigned)E;   // sentinel
}

// single placement pass: cursors preloaded from slab, only LDS atomics.
__global__ void k_part2(const int* __restrict__ row, const int* __restrict__ col,
                        const unsigned* __restrict__ wgHist,
                        const unsigned* __restrict__ baseR, const unsigned* __restrict__ baseC,
                        unsigned* __restrict__ entries, unsigned short* __restrict__ colslab,
                        int E) {
    __shared__ unsigned cR[256];
    __shared__ unsigned cC[256];
    int t = threadIdx.x;
    const unsigned* my = wgHist + (size_t)blockIdx.x * 512;
    cR[t] = my[t] + baseR[t];
    cC[t] = my[t + 256] + baseC[t];
    __syncthreads();
    long long c0 = (long long)blockIdx.x * CHUNK;
    for (int k = 0; k < CHUNK / 256; ++k) {
        long long e = c0 + (long long)k * 256 + t;
        if (e < E) {
            int r = row[e], cc = col[e];
            unsigned pr = atomicAdd(&cR[r >> LOG_BKT], 1u);
            entries[pr] = ((unsigned)(r & (BKT_W - 1)) << 17) | (unsigned)cc;
            unsigned pc = atomicAdd(&cC[cc >> LOG_BKT], 1u);
            colslab[pc] = (unsigned short)(cc & (BKT_W - 1));
        }
    }
}

// fused independent mid-work: blocks [0,nBkt) do colcount (dis), [nBkt,2nBkt) localcsr.
__global__ void __launch_bounds__(256) k_mid(
        const unsigned* __restrict__ entries, unsigned* __restrict__ sorted,
        const unsigned* __restrict__ baseR, unsigned* __restrict__ nodeBeg,
        const unsigned short* __restrict__ colslab, const unsigned* __restrict__ baseC,
        float* __restrict__ dis, int N, int nBkt) {
    __shared__ unsigned shA[512];   // hist
    __shared__ unsigned shB[512];   // cur
    __shared__ unsigned shC[256];   // scan temp
    int b = blockIdx.x, t = threadIdx.x;
    if (b < nBkt) {
        // ---- colcount: dis[node] = rsqrt(cnt+1) ----
        shA[t] = 0u; shA[t + 256] = 0u;
        __syncthreads();
        unsigned s = baseC[b], e_ = baseC[b + 1];
        for (unsigned i = s + t; i < e_; i += 256) atomicAdd(&shA[colslab[i]], 1u);
        __syncthreads();
        int node0 = b << LOG_BKT;
        int n0 = node0 + t, n1 = node0 + t + 256;
        if (n0 < N) dis[n0] = rsqrtf((float)(shA[t] + 1u));
        if (n1 < N) dis[n1] = rsqrtf((float)(shA[t + 256] + 1u));
    } else {
        // ---- localcsr: per-node CSR within bucket ----
        b -= nBkt;
        shA[t] = 0u; shA[t + 256] = 0u;
        __syncthreads();
        unsigned s = baseR[b], e_ = baseR[b + 1];
        int cnt = (int)(e_ - s);
        for (int i = t; i < cnt; i += 256) atomicAdd(&shA[entries[s + i] >> 17], 1u);
        __syncthreads();
        unsigned a = shA[2 * t], bb = shA[2 * t + 1], s2 = a + bb;
        shC[t] = s2;
        __syncthreads();
        for (int d = 1; d < 256; d <<= 1) {
            unsigned ad = (t >= d) ? shC[t - d] : 0u;
            __syncthreads();
            shC[t] += ad;
            __syncthreads();
        }
        unsigned excl = shC[t] - s2;
        shB[2 * t] = excl; shB[2 * t + 1] = excl + a;
        int node0 = b << LOG_BKT;
        int n0 = node0 + 2 * t, n1 = n0 + 1;
        if (n0 < N) nodeBeg[n0] = s + excl;
        if (n1 < N) nodeBeg[n1] = s + excl + a;
        __syncthreads();
        for (int i = t; i < cnt; i += 256) {
            unsigned v = entries[s + i];
            unsigned pos = atomicAdd(&shB[v >> 17], 1u);
            sorted[s + pos] = v & 0x1FFFFu;
        }
    }
}

// xs = dis * x, fp16
__global__ void k_scale(const float* __restrict__ x, const float* __restrict__ dis,
                        __half* __restrict__ xs, int N) {
    int i = blockIdx.x * blockDim.x + threadIdx.x;
    if (i >= N * (D_FEAT / 4)) return;
    int node = i >> 4;
    float d = dis[node];
    float4 v = ((const float4*)x)[i];
    __half2 p0 = __floats2half2_rn(d * v.x, d * v.y);
    __half2 p1 = __floats2half2_rn(d * v.z, d * v.w);
    ((__half2*)xs)[i * 2]     = p0;
    ((__half2*)xs)[i * 2 + 1] = p1;
}

// per-node wave gather (proven): 2 groups x 32 lanes, lane owns feats (2m,2m+1);
// group 0 even-position cols, group 1 odd; __half2 4B loads; f32 self term;
// combine via shfl(lane^32).
__global__ void __launch_bounds__(256) k_gather(
        const float* __restrict__ x, const __half* __restrict__ xs,
        const float* __restrict__ dis, const unsigned* __restrict__ nodeBeg,
        const unsigned* __restrict__ sorted, float* __restrict__ out, int n) {
    int r = (blockIdx.x * blockDim.x + threadIdx.x) >> 6;
    int lane = threadIdx.x & 63;
    if (r >= n) return;
    int g = lane >> 5, m = lane & 31;
    float dr = dis[r];
    float2 acc;
    if (g == 0) {
        float2 xv = ((const float2*)x)[(size_t)r * 32 + m];
        acc.x = dr * xv.x; acc.y = dr * xv.y;          // self term (final *dr below)
    } else {
        acc.x = 0.f; acc.y = 0.f;
    }
    unsigned s = nodeBeg[r], e_ = nodeBeg[r + 1];
    int cnt = (int)(e_ - s);
    const __half2* xs2 = (const __half2*)xs;
    for (int base = 0; base < cnt; base += 64) {
        int mm = min(64, cnt - base);
        unsigned my_e = (lane < mm) ? sorted[s + base + lane] : 0u;
        int k = 0;
        for (; k + 8 <= mm; k += 8) {
            unsigned c0 = __shfl(my_e, k + g),     c1 = __shfl(my_e, k + 2 + g);
            unsigned c2 = __shfl(my_e, k + 4 + g), c3 = __shfl(my_e, k + 6 + g);
            float2 f0 = __half22float2(xs2[(size_t)c0 * 32 + m]);
            float2 f1 = __half22float2(xs2[(size_t)c1 * 32 + m]);
            float2 f2 = __half22float2(xs2[(size_t)c2 * 32 + m]);
            float2 f3 = __half22float2(xs2[(size_t)c3 * 32 + m]);
            acc.x += (f0.x + f1.x) + (f2.x + f3.x);
            acc.y += (f0.y + f1.y) + (f2.y + f3.y);
        }
        for (; k < mm; k += 2) {
            if (k + g < mm) {
                unsigned c = __shfl(my_e, k + g);
                float2 f = __half22float2(xs2[(size_t)c * 32 + m]);
                acc.x += f.x; acc.y += f.y;
            }
        }
    }
    acc.x += __shfl(acc.x, lane ^ 32);
    acc.y += __shfl(acc.y, lane ^ 32);
    if (g == 0) {
        float2 o; o.x = dr * acc.x; o.y = dr * acc.y;
        ((float2*)out)[(size_t)r * 32 + m] = o;
    }
}

// ---------------- fallback path (round-1 atomic scatter) ----------------

__global__ void k_init_deg(float* __restrict__ deg, int n) {
    int i = blockIdx.x * blockDim.x + threadIdx.x;
    if (i < n) deg[i] = 1.0f;
}
__global__ void k_count_deg(const int* __restrict__ col, float* __restrict__ deg, int E) {
    int e = blockIdx.x * blockDim.x + threadIdx.x;
    if (e < E) atomicAdd(&deg[col[e]], 1.0f);
}
__global__ void k_deg_to_dis(float* __restrict__ deg, int n) {
    int i = blockIdx.x * blockDim.x + threadIdx.x;
    if (i < n) deg[i] = rsqrtf(deg[i]);
}
__global__ void k_self_init(const float* __restrict__ x, const float* __restrict__ dis,
                            float* __restrict__ out, int total) {
    int idx = blockIdx.x * blockDim.x + threadIdx.x;
    if (idx < total) {
        int node = idx >> 6;
        float s = dis[node];
        out[idx] = s * s * x[idx];
    }
}
__global__ void k_scatter(const int* __restrict__ row, const int* __restrict__ col,
                          const float* __restrict__ x, const float* __restrict__ dis,
                          float* __restrict__ out, int E) {
    int gtid = blockIdx.x * blockDim.x + threadIdx.x;
    int edge = gtid >> 6;
    int lane = threadIdx.x & 63;
    if (edge < E) {
        int r = row[edge];
        int c = col[edge];
        float nrm = dis[r] * dis[c];
        atomicAdd(&out[r * D_FEAT + lane], nrm * x[c * D_FEAT + lane]);
    }
}

extern "C" void kernel_launch(void* const* d_in, const int* in_sizes, int n_in,
                              void* d_out, int out_size, void* d_ws, size_t ws_size,
                              hipStream_t stream) {
    const float* x = (const float*)d_in[0];
    const int* ei = (const int*)d_in[1];

    const int N = in_sizes[0] / D_FEAT;   // 100000
    const int E = in_sizes[1] / 2;        // 1000000
    const int* row = ei;
    const int* col = ei + E;

    float* out = (float*)d_out;
    const int B = 256;
    const int nBkt = (N + BKT_W - 1) >> LOG_BKT;
    const int nWG = (E + CHUNK - 1) / CHUNK;

    // ws words: dis[N] | baseR[257] | baseC[257] | binTot[512] | nodeBeg[N+1] | pad
    //           | sorted[E] (wgHist[nWG*512] overlays its head until part2)
    //           | tail: max(entries[E]*4 + colslab[E]*2, xs N*128B)
    size_t preSorted = (size_t)N + 257 + 257 + 512 + (size_t)(N + 1);
    preSorted = (preSorted + 3) & ~(size_t)3;       // 16B-align sorted/entries/xs
    size_t tailBytes = (size_t)E * 6;
    size_t xsBytes = (size_t)N * D_FEAT * 2;
    if (xsBytes > tailBytes) tailBytes = xsBytes;
    size_t need = (preSorted + (size_t)E) * 4 + tailBytes;

    if (N <= 131072 && nBkt <= NBIN && nWG <= MAXWG &&
        (size_t)nWG * 512 <= (size_t)E && ws_size >= need) {
        float*    dis     = (float*)d_ws;
        unsigned* baseR   = (unsigned*)(dis + N);
        unsigned* baseC   = baseR + 257;
        unsigned* binTot  = baseC + 257;
        unsigned* nodeBeg = binTot + 512;
        unsigned* sorted  = (unsigned*)d_ws + preSorted;
        unsigned* wgHist  = sorted;                    // overlays sorted until part2
        unsigned* entries = sorted + E;                // tail
        unsigned short* colslab = (unsigned short*)(entries + E);
        __half*   xs      = (__half*)entries;          // overlays entries+colslab after mid

        k_histdump<<<nWG, B, 0, stream>>>(row, col, wgHist, E);
        k_scan2aT<<<16, B, 0, stream>>>(wgHist, binTot, nWG);
        k_scan2b<<<1, B, 0, stream>>>(binTot, baseR, baseC, nodeBeg, E, N);
        k_part2<<<nWG, B, 0, stream>>>(row, col, wgHist, baseR, baseC, entries, colslab, E);
        k_mid<<<2 * nBkt, B, 0, stream>>>(entries, sorted, baseR, nodeBeg,
                                          colslab, baseC, dis, N, nBkt);
        k_scale<<<(N * (D_FEAT / 4) + B - 1) / B, B, 0, stream>>>(x, dis, xs, N);
        long long gthreads = (long long)N * 64;
        k_gather<<<(int)((gthreads + B - 1) / B), B, 0, stream>>>(
            x, xs, dis, nodeBeg, sorted, out, N);
    } else {
        // fallback: atomic scatter (needs only N floats of ws)
        float* deg = (float*)d_ws;
        k_init_deg<<<(N + B - 1) / B, B, 0, stream>>>(deg, N);
        k_count_deg<<<(E + B - 1) / B, B, 0, stream>>>(col, deg, E);
        k_deg_to_dis<<<(N + B - 1) / B, B, 0, stream>>>(deg, N);
        int total = N * D_FEAT;
        k_self_init<<<(total + B - 1) / B, B, 0, stream>>>(x, deg, out, total);
        long long st = (long long)E * 64;
        k_scatter<<<(int)((st + B - 1) / B), B, 0, stream>>>(row, col, x, deg, out, E);
    }
}

// Round 12
// 101.605 us; speedup vs baseline: 3.0665x; 1.2175x over previous
//
#include <hip/hip_runtime.h>
#include <hip/hip_fp16.h>

#define D_FEAT 64
#define LOG_BKT 9
#define BKT_W 512            // nodes per bucket
#define NBIN 256             // bins (N <= 131072)
#define CHUNK 4096           // edges per WG in histdump/part (245 WGs at E=1M)

// ---------------- fast path ----------------

// per-WG 512-bin histogram (row bins 0..255, col bins 256..511) -> global slab.
// Plain stores: no zeroing kernel, no global atomics.
__global__ void k_histdump(const int* __restrict__ row, const int* __restrict__ col,
                           unsigned* __restrict__ wgHist, int E) {
    __shared__ unsigned h[512];
    int t = threadIdx.x;
    h[t] = 0u; h[t + 256] = 0u;
    __syncthreads();
    long long c0 = (long long)blockIdx.x * CHUNK;
    for (int k = 0; k < CHUNK / 256; ++k) {
        long long e = c0 + (long long)k * 256 + t;
        if (e < E) {
            atomicAdd(&h[row[e] >> LOG_BKT], 1u);
            atomicAdd(&h[256 + (col[e] >> LOG_BKT)], 1u);
        }
    }
    __syncthreads();
    unsigned* dst = wgHist + (size_t)blockIdx.x * 512;
    dst[t] = h[t]; dst[t + 256] = h[t + 256];
}

// one block per bin: exclusive prefix over WGs (in-place cursors), total -> binTot.
// WG pair order (t, t+256) is arbitrary but fixed: ranges are disjoint and tile.
// (512 blocks: scattered but fully parallel — proven faster than coalesced/starved.)
__global__ void k_scan2a(unsigned* __restrict__ wgHist, unsigned* __restrict__ binTot,
                         int nWG) {
    __shared__ unsigned lds[256];
    int b = blockIdx.x, t = threadIdx.x;
    unsigned v0 = (t < nWG) ? wgHist[(size_t)t * 512 + b] : 0u;
    unsigned v1 = (t + 256 < nWG) ? wgHist[(size_t)(t + 256) * 512 + b] : 0u;
    unsigned s = v0 + v1;
    lds[t] = s;
    __syncthreads();
    for (int d = 1; d < 256; d <<= 1) {
        unsigned a = (t >= d) ? lds[t - d] : 0u;
        __syncthreads();
        lds[t] += a;
        __syncthreads();
    }
    unsigned excl = lds[t] - s;
    if (t < nWG) wgHist[(size_t)t * 512 + b] = excl;
    if (t + 256 < nWG) wgHist[(size_t)(t + 256) * 512 + b] = excl + v0;
    if (t == 255) binTot[b] = lds[255];
}

// placement pass; each block re-derives the 512-bin base scan from binTot in LDS
// (replaces the scan2b dispatch); block 0 publishes baseR/baseC + sentinels for k_mid.
__global__ void __launch_bounds__(256) k_part2(
        const int* __restrict__ row, const int* __restrict__ col,
        const unsigned* __restrict__ wgHist, const unsigned* __restrict__ binTot,
        unsigned* __restrict__ baseR, unsigned* __restrict__ baseC,
        unsigned* __restrict__ nodeBeg,
        unsigned* __restrict__ entries, unsigned short* __restrict__ colslab,
        int E, int N) {
    __shared__ unsigned lds[256];
    __shared__ unsigned cR[256];
    __shared__ unsigned cC[256];
    int t = threadIdx.x;
    // scan row-bin totals -> bR
    unsigned v = binTot[t];
    lds[t] = v;
    __syncthreads();
    for (int d = 1; d < 256; d <<= 1) {
        unsigned a = (t >= d) ? lds[t - d] : 0u;
        __syncthreads();
        lds[t] += a;
        __syncthreads();
    }
    unsigned bR = lds[t] - v;
    __syncthreads();
    // scan col-bin totals -> bC
    unsigned w = binTot[256 + t];
    lds[t] = w;
    __syncthreads();
    for (int d = 1; d < 256; d <<= 1) {
        unsigned a = (t >= d) ? lds[t - d] : 0u;
        __syncthreads();
        lds[t] += a;
        __syncthreads();
    }
    unsigned bC = lds[t] - w;
    const unsigned* my = wgHist + (size_t)blockIdx.x * 512;
    cR[t] = my[t] + bR;
    cC[t] = my[t + 256] + bC;
    if (blockIdx.x == 0) {
        baseR[t] = bR; baseC[t] = bC;
        if (t == 255) { baseR[256] = (unsigned)E; baseC[256] = (unsigned)E; }
        if (t == 0) nodeBeg[N] = (unsigned)E;   // sentinel
    }
    __syncthreads();
    long long c0 = (long long)blockIdx.x * CHUNK;
    for (int k = 0; k < CHUNK / 256; ++k) {
        long long e = c0 + (long long)k * 256 + t;
        if (e < E) {
            int r = row[e], cc = col[e];
            unsigned pr = atomicAdd(&cR[r >> LOG_BKT], 1u);
            entries[pr] = ((unsigned)(r & (BKT_W - 1)) << 17) | (unsigned)cc;
            unsigned pc = atomicAdd(&cC[cc >> LOG_BKT], 1u);
            colslab[pc] = (unsigned short)(cc & (BKT_W - 1));
        }
    }
}

// fused independent mid-work: blocks [0,nBkt) do colcount (dis), [nBkt,2nBkt) localcsr.
__global__ void __launch_bounds__(256) k_mid(
        const unsigned* __restrict__ entries, unsigned* __restrict__ sorted,
        const unsigned* __restrict__ baseR, unsigned* __restrict__ nodeBeg,
        const unsigned short* __restrict__ colslab, const unsigned* __restrict__ baseC,
        float* __restrict__ dis, int N, int nBkt) {
    __shared__ unsigned shA[512];   // hist
    __shared__ unsigned shB[512];   // cur
    __shared__ unsigned shC[256];   // scan temp
    int b = blockIdx.x, t = threadIdx.x;
    if (b < nBkt) {
        // ---- colcount: dis[node] = rsqrt(cnt+1) ----
        shA[t] = 0u; shA[t + 256] = 0u;
        __syncthreads();
        unsigned s = baseC[b], e_ = baseC[b + 1];
        for (unsigned i = s + t; i < e_; i += 256) atomicAdd(&shA[colslab[i]], 1u);
        __syncthreads();
        int node0 = b << LOG_BKT;
        int n0 = node0 + t, n1 = node0 + t + 256;
        if (n0 < N) dis[n0] = rsqrtf((float)(shA[t] + 1u));
        if (n1 < N) dis[n1] = rsqrtf((float)(shA[t + 256] + 1u));
    } else {
        // ---- localcsr: per-node CSR within bucket ----
        b -= nBkt;
        shA[t] = 0u; shA[t + 256] = 0u;
        __syncthreads();
        unsigned s = baseR[b], e_ = baseR[b + 1];
        int cnt = (int)(e_ - s);
        for (int i = t; i < cnt; i += 256) atomicAdd(&shA[entries[s + i] >> 17], 1u);
        __syncthreads();
        unsigned a = shA[2 * t], bb = shA[2 * t + 1], s2 = a + bb;
        shC[t] = s2;
        __syncthreads();
        for (int d = 1; d < 256; d <<= 1) {
            unsigned ad = (t >= d) ? shC[t - d] : 0u;
            __syncthreads();
            shC[t] += ad;
            __syncthreads();
        }
        unsigned excl = shC[t] - s2;
        shB[2 * t] = excl; shB[2 * t + 1] = excl + a;
        int node0 = b << LOG_BKT;
        int n0 = node0 + 2 * t, n1 = n0 + 1;
        if (n0 < N) nodeBeg[n0] = s + excl;
        if (n1 < N) nodeBeg[n1] = s + excl + a;
        __syncthreads();
        for (int i = t; i < cnt; i += 256) {
            unsigned v = entries[s + i];
            unsigned pos = atomicAdd(&shB[v >> 17], 1u);
            sorted[s + pos] = v & 0x1FFFFu;
        }
    }
}

// xs = dis * x, fp16
__global__ void k_scale(const float* __restrict__ x, const float* __restrict__ dis,
                        __half* __restrict__ xs, int N) {
    int i = blockIdx.x * blockDim.x + threadIdx.x;
    if (i >= N * (D_FEAT / 4)) return;
    int node = i >> 4;
    float d = dis[node];
    float4 v = ((const float4*)x)[i];
    __half2 p0 = __floats2half2_rn(d * v.x, d * v.y);
    __half2 p1 = __floats2half2_rn(d * v.z, d * v.w);
    ((__half2*)xs)[i * 2]     = p0;
    ((__half2*)xs)[i * 2 + 1] = p1;
}

// per-node wave gather (proven): 2 groups x 32 lanes, lane owns feats (2m,2m+1);
// group 0 even-position cols, group 1 odd; __half2 4B loads; f32 self term;
// combine via shfl(lane^32).
__global__ void __launch_bounds__(256) k_gather(
        const float* __restrict__ x, const __half* __restrict__ xs,
        const float* __restrict__ dis, const unsigned* __restrict__ nodeBeg,
        const unsigned* __restrict__ sorted, float* __restrict__ out, int n) {
    int r = (blockIdx.x * blockDim.x + threadIdx.x) >> 6;
    int lane = threadIdx.x & 63;
    if (r >= n) return;
    int g = lane >> 5, m = lane & 31;
    float dr = dis[r];
    float2 acc;
    if (g == 0) {
        float2 xv = ((const float2*)x)[(size_t)r * 32 + m];
        acc.x = dr * xv.x; acc.y = dr * xv.y;          // self term (final *dr below)
    } else {
        acc.x = 0.f; acc.y = 0.f;
    }
    unsigned s = nodeBeg[r], e_ = nodeBeg[r + 1];
    int cnt = (int)(e_ - s);
    const __half2* xs2 = (const __half2*)xs;
    for (int base = 0; base < cnt; base += 64) {
        int mm = min(64, cnt - base);
        unsigned my_e = (lane < mm) ? sorted[s + base + lane] : 0u;
        int k = 0;
        for (; k + 8 <= mm; k += 8) {
            unsigned c0 = __shfl(my_e, k + g),     c1 = __shfl(my_e, k + 2 + g);
            unsigned c2 = __shfl(my_e, k + 4 + g), c3 = __shfl(my_e, k + 6 + g);
            float2 f0 = __half22float2(xs2[(size_t)c0 * 32 + m]);
            float2 f1 = __half22float2(xs2[(size_t)c1 * 32 + m]);
            float2 f2 = __half22float2(xs2[(size_t)c2 * 32 + m]);
            float2 f3 = __half22float2(xs2[(size_t)c3 * 32 + m]);
            acc.x += (f0.x + f1.x) + (f2.x + f3.x);
            acc.y += (f0.y + f1.y) + (f2.y + f3.y);
        }
        for (; k < mm; k += 2) {
            if (k + g < mm) {
                unsigned c = __shfl(my_e, k + g);
                float2 f = __half22float2(xs2[(size_t)c * 32 + m]);
                acc.x += f.x; acc.y += f.y;
            }
        }
    }
    acc.x += __shfl(acc.x, lane ^ 32);
    acc.y += __shfl(acc.y, lane ^ 32);
    if (g == 0) {
        float2 o; o.x = dr * acc.x; o.y = dr * acc.y;
        ((float2*)out)[(size_t)r * 32 + m] = o;
    }
}

// ---------------- fallback path (round-1 atomic scatter) ----------------

__global__ void k_init_deg(float* __restrict__ deg, int n) {
    int i = blockIdx.x * blockDim.x + threadIdx.x;
    if (i < n) deg[i] = 1.0f;
}
__global__ void k_count_deg(const int* __restrict__ col, float* __restrict__ deg, int E) {
    int e = blockIdx.x * blockDim.x + threadIdx.x;
    if (e < E) atomicAdd(&deg[col[e]], 1.0f);
}
__global__ void k_deg_to_dis(float* __restrict__ deg, int n) {
    int i = blockIdx.x * blockDim.x + threadIdx.x;
    if (i < n) deg[i] = rsqrtf(deg[i]);
}
__global__ void k_self_init(const float* __restrict__ x, const float* __restrict__ dis,
                            float* __restrict__ out, int total) {
    int idx = blockIdx.x * blockDim.x + threadIdx.x;
    if (idx < total) {
        int node = idx >> 6;
        float s = dis[node];
        out[idx] = s * s * x[idx];
    }
}
__global__ void k_scatter(const int* __restrict__ row, const int* __restrict__ col,
                          const float* __restrict__ x, const float* __restrict__ dis,
                          float* __restrict__ out, int E) {
    int gtid = blockIdx.x * blockDim.x + threadIdx.x;
    int edge = gtid >> 6;
    int lane = threadIdx.x & 63;
    if (edge < E) {
        int r = row[edge];
        int c = col[edge];
        float nrm = dis[r] * dis[c];
        atomicAdd(&out[r * D_FEAT + lane], nrm * x[c * D_FEAT + lane]);
    }
}

extern "C" void kernel_launch(void* const* d_in, const int* in_sizes, int n_in,
                              void* d_out, int out_size, void* d_ws, size_t ws_size,
                              hipStream_t stream) {
    const float* x = (const float*)d_in[0];
    const int* ei = (const int*)d_in[1];

    const int N = in_sizes[0] / D_FEAT;   // 100000
    const int E = in_sizes[1] / 2;        // 1000000
    const int* row = ei;
    const int* col = ei + E;

    float* out = (float*)d_out;
    const int B = 256;
    const int nBkt = (N + BKT_W - 1) >> LOG_BKT;
    const int nWG = (E + CHUNK - 1) / CHUNK;

    // ws words: dis[N] | baseR[257] | baseC[257] | binTot[512] | nodeBeg[N+1] | pad
    //           | sorted[E] (wgHist[nWG*512] overlays its head until part2)
    //           | tail: max(entries[E]*4 + colslab[E]*2, xs N*128B)
    size_t preSorted = (size_t)N + 257 + 257 + 512 + (size_t)(N + 1);
    preSorted = (preSorted + 3) & ~(size_t)3;       // 16B-align sorted/entries/xs
    size_t tailBytes = (size_t)E * 6;
    size_t xsBytes = (size_t)N * D_FEAT * 2;
    if (xsBytes > tailBytes) tailBytes = xsBytes;
    size_t need = (preSorted + (size_t)E) * 4 + tailBytes;

    if (N <= 131072 && nBkt <= NBIN && nWG <= 512 &&
        (size_t)nWG * 512 <= (size_t)E && ws_size >= need) {
        float*    dis     = (float*)d_ws;
        unsigned* baseR   = (unsigned*)(dis + N);
        unsigned* baseC   = baseR + 257;
        unsigned* binTot  = baseC + 257;
        unsigned* nodeBeg = binTot + 512;
        unsigned* sorted  = (unsigned*)d_ws + preSorted;
        unsigned* wgHist  = sorted;                    // overlays sorted until part2
        unsigned* entries = sorted + E;                // tail
        unsigned short* colslab = (unsigned short*)(entries + E);
        __half*   xs      = (__half*)entries;          // overlays entries+colslab after mid

        k_histdump<<<nWG, B, 0, stream>>>(row, col, wgHist, E);
        k_scan2a<<<512, B, 0, stream>>>(wgHist, binTot, nWG);
        k_part2<<<nWG, B, 0, stream>>>(row, col, wgHist, binTot, baseR, baseC,
                                       nodeBeg, entries, colslab, E, N);
        k_mid<<<2 * nBkt, B, 0, stream>>>(entries, sorted, baseR, nodeBeg,
                                          colslab, baseC, dis, N, nBkt);
        k_scale<<<(N * (D_FEAT / 4) + B - 1) / B, B, 0, stream>>>(x, dis, xs, N);
        long long gthreads = (long long)N * 64;
        k_gather<<<(int)((gthreads + B - 1) / B), B, 0, stream>>>(
            x, xs, dis, nodeBeg, sorted, out, N);
    } else {
        // fallback: atomic scatter (needs only N floats of ws)
        float* deg = (float*)d_ws;
        k_init_deg<<<(N + B - 1) / B, B, 0, stream>>>(deg, N);
        k_count_deg<<<(E + B - 1) / B, B, 0, stream>>>(col, deg, E);
        k_deg_to_dis<<<(N + B - 1) / B, B, 0, stream>>>(deg, N);
        int total = N * D_FEAT;
        k_self_init<<<(total + B - 1) / B, B, 0, stream>>>(x, deg, out, total);
        long long st = (long long)E * 64;
        k_scatter<<<(int)((st + B - 1) / B), B, 0, stream>>>(row, col, x, deg, out, E);
    }
}